// Round 2
// baseline (786.413 us; speedup 1.0000x reference)
//
#include <hip/hip_runtime.h>
#include <hip/hip_bf16.h>
#include <math.h>

typedef __attribute__((ext_vector_type(8))) short bf16x8;
typedef __attribute__((ext_vector_type(4))) float f32x4;
typedef __attribute__((ext_vector_type(8))) unsigned short u16x8;

#define MFMA16(a, b, c) __builtin_amdgcn_mfma_f32_16x16x32_bf16(a, b, c, 0, 0, 0)

__device__ __forceinline__ unsigned short f2b(float f) {
  __hip_bfloat16 h = __float2bfloat16(f);
  return *reinterpret_cast<unsigned short*>(&h);
}

// load 8 fp32, return 8 bf16 packed in a uint4
__device__ __forceinline__ uint4 cvt8(const float* __restrict__ p) {
  float4 a = *(const float4*)p;
  float4 b = *(const float4*)(p + 4);
  union {
    unsigned short us[8];
    uint4 u;
  } r;
  r.us[0] = f2b(a.x); r.us[1] = f2b(a.y); r.us[2] = f2b(a.z); r.us[3] = f2b(a.w);
  r.us[4] = f2b(b.x); r.us[5] = f2b(b.y); r.us[6] = f2b(b.z); r.us[7] = f2b(b.w);
  return r.u;
}

// out_bf16[c][r] = bf16(in_f32[r][c]); R, C multiples of 64
__global__ __launch_bounds__(256) void transpose_f32_bf16(
    const float* __restrict__ in, unsigned short* __restrict__ out, int R,
    int C) {
  __shared__ unsigned short tile[64][72];
  const int tR = blockIdx.y * 64, tC = blockIdx.x * 64;
  const int t = threadIdx.x;
#pragma unroll
  for (int p = 0; p < 4; ++p) {
    int u = t + p * 256, r = u >> 4, c = (u & 15) * 4;
    float4 v = *(const float4*)&in[(size_t)(tR + r) * C + tC + c];
    tile[r][c] = f2b(v.x);
    tile[r][c + 1] = f2b(v.y);
    tile[r][c + 2] = f2b(v.z);
    tile[r][c + 3] = f2b(v.w);
  }
  __syncthreads();
#pragma unroll
  for (int p = 0; p < 2; ++p) {
    int u = t + p * 256, orow = u >> 3, oc = (u & 7) * 8;
    u16x8 v;
#pragma unroll
    for (int e = 0; e < 8; ++e) v[e] = tile[oc + e][orow];
    *(u16x8*)&out[(size_t)(tC + orow) * R + tR + oc] = v;
  }
}

// C[M][N] = A[M][K] * Bt[N][K]^T, 128x128 tile, 4 waves, 16x16x32 MFMA.
// MODE 0: A is fp32 (converted to bf16 during staging); epilogue splits into
//         Q*scale / K / V^T head layouts (bf16).
// MODE 1: A is bf16; epilogue adds fp32 bias, stores fp32 row-major.
template <int MODE>
__global__ __launch_bounds__(256, 2) void gemm_bt(
    const void* __restrict__ Av, const unsigned short* __restrict__ Bt,
    unsigned short* __restrict__ O0, unsigned short* __restrict__ O1,
    unsigned short* __restrict__ O2, float* __restrict__ OF,
    const float* __restrict__ bias, int K, int N) {
  __shared__ unsigned short sA[128][40];
  __shared__ unsigned short sB[128][40];
  const int m0 = blockIdx.y * 128, n0 = blockIdx.x * 128;
  const int t = threadIdx.x;
  const int wave = t >> 6, lane = t & 63, quad = lane >> 4, t16 = lane & 15;
  const int wr = (wave >> 1) * 64, wc = (wave & 1) * 64;
  const int sr = t >> 2, sc = (t & 3) * 8;

  f32x4 acc[4][4];
#pragma unroll
  for (int i = 0; i < 4; ++i)
#pragma unroll
    for (int j = 0; j < 4; ++j) acc[i][j] = (f32x4){0.f, 0.f, 0.f, 0.f};

  const float* Af = (const float*)Av;
  const unsigned short* Ab = (const unsigned short*)Av;
  const size_t arow = (size_t)(m0 + sr) * K + sc;
  const size_t rowK64 = (size_t)64 * K;
  const unsigned short* Bp = Bt + (size_t)(n0 + sr) * K + sc;

  for (int k0 = 0; k0 < K; k0 += 32) {
    uint4 a0, a1;
    if (MODE == 0) {
      a0 = cvt8(Af + arow + k0);
      a1 = cvt8(Af + arow + rowK64 + k0);
    } else {
      a0 = *(const uint4*)(Ab + arow + k0);
      a1 = *(const uint4*)(Ab + arow + rowK64 + k0);
    }
    uint4 b0 = *(const uint4*)(Bp + k0);
    uint4 b1 = *(const uint4*)(Bp + rowK64 + k0);
    __syncthreads();
    *(uint4*)&sA[sr][sc] = a0;
    *(uint4*)&sA[sr + 64][sc] = a1;
    *(uint4*)&sB[sr][sc] = b0;
    *(uint4*)&sB[sr + 64][sc] = b1;
    __syncthreads();
    bf16x8 af[4], bf[4];
#pragma unroll
    for (int i = 0; i < 4; ++i)
      af[i] = *(const bf16x8*)&sA[wr + i * 16 + t16][quad * 8];
#pragma unroll
    for (int j = 0; j < 4; ++j)
      bf[j] = *(const bf16x8*)&sB[wc + j * 16 + t16][quad * 8];
#pragma unroll
    for (int i = 0; i < 4; ++i)
#pragma unroll
      for (int j = 0; j < 4; ++j) acc[i][j] = MFMA16(af[i], bf[j], acc[i][j]);
  }

#pragma unroll
  for (int i = 0; i < 4; ++i) {
    const int mrow = m0 + wr + i * 16 + quad * 4;  // + r
#pragma unroll
    for (int j = 0; j < 4; ++j) {
      const int ncol = n0 + wc + j * 16 + t16;
#pragma unroll
      for (int r = 0; r < 4; ++r) {
        const float v = acc[i][j][r];
        const int mr = mrow + r;
        if (MODE == 0) {
          const int bb = mr >> 11, nn = mr & 2047;
          const int sec = ncol >> 10, rem = ncol & 1023;
          const int hh = rem >> 6, dd = rem & 63;
          const size_t bhh = (size_t)bb * 16 + hh;
          if (sec == 0)
            O0[(bhh * 2048 + nn) * 64 + dd] = f2b(v * 0.125f);  // Q * scale
          else if (sec == 1)
            O1[(bhh * 2048 + nn) * 64 + dd] = f2b(v);  // K
          else
            O2[(bhh * 64 + dd) * 2048 + nn] = f2b(v);  // V^T
        } else {
          OF[(size_t)mr * N + ncol] = v + bias[ncol];
        }
      }
    }
  }
}

// Flash attention: block = (b,h, 64-row q tile), 4 waves of 16 q rows each.
// Q/K/V^T are bf16 head-layout buffers; pos_bias is fp32, staged into LDS.
__global__ __launch_bounds__(256, 2) void attn_kernel(
    const unsigned short* __restrict__ Q, const unsigned short* __restrict__ Kb,
    const unsigned short* __restrict__ Vt, const float* __restrict__ PB,
    unsigned short* __restrict__ Ao) {
  __shared__ unsigned short sQ[64][72];
  __shared__ unsigned short sK[64][72];
  __shared__ unsigned short sV[64][72];  // sV[d][key]
  __shared__ float sBi[64][68];          // pos_bias tile [q][k], fp32
  __shared__ unsigned short sP[4][16][72];

  const int bh = blockIdx.x >> 5;
  const int qt = blockIdx.x & 31;
  const int h = bh & 15;
  const int b = bh >> 4;
  const int q0 = qt * 64;
  const int t = threadIdx.x;
  const int wave = t >> 6, lane = t & 63, quad = lane >> 4, t16 = lane & 15;

  const size_t qbase = ((size_t)bh * 2048 + q0) * 64;
#pragma unroll
  for (int p = 0; p < 2; ++p) {
    int u = t + p * 256, r = u >> 3, c = (u & 7) * 8;
    *(uint4*)&sQ[r][c] = *(const uint4*)&Q[qbase + r * 64 + c];
  }
  __syncthreads();
  const bf16x8 qa0 = *(const bf16x8*)&sQ[wave * 16 + t16][quad * 8];
  const bf16x8 qa1 = *(const bf16x8*)&sQ[wave * 16 + t16][32 + quad * 8];

  f32x4 accO[4];
  float m_r[4], l_r[4];
#pragma unroll
  for (int i = 0; i < 4; ++i) {
    accO[i] = (f32x4){0.f, 0.f, 0.f, 0.f};
    m_r[i] = -INFINITY;
    l_r[i] = 0.f;
  }

  const int qrow = q0 + wave * 16 + quad * 4;  // + r
  const int r0 = t >> 3, c0 = (t & 7) * 8;     // bf16 tile staging coords
  const int rb = t >> 4, cb = (t & 15) * 4;    // fp32 bias staging coords

  for (int kt = 0; kt <= qt; ++kt) {
    const int k0 = kt * 64;
    const size_t kbase = ((size_t)bh * 2048 + k0) * 64;
    const size_t vbase = (size_t)bh * 64 * 2048 + k0;
    const size_t bbase = (size_t)h * 2048 * 2048 + (size_t)q0 * 2048 + k0;
    uint4 kv0 = *(const uint4*)&Kb[kbase + r0 * 64 + c0];
    uint4 kv1 = *(const uint4*)&Kb[kbase + (r0 + 32) * 64 + c0];
    uint4 vv0 = *(const uint4*)&Vt[vbase + (size_t)r0 * 2048 + c0];
    uint4 vv1 = *(const uint4*)&Vt[vbase + (size_t)(r0 + 32) * 2048 + c0];
    float4 bv0 = *(const float4*)&PB[bbase + (size_t)rb * 2048 + cb];
    float4 bv1 = *(const float4*)&PB[bbase + (size_t)(rb + 16) * 2048 + cb];
    float4 bv2 = *(const float4*)&PB[bbase + (size_t)(rb + 32) * 2048 + cb];
    float4 bv3 = *(const float4*)&PB[bbase + (size_t)(rb + 48) * 2048 + cb];
    __syncthreads();  // previous tile's LDS reads complete
    *(uint4*)&sK[r0][c0] = kv0;
    *(uint4*)&sK[r0 + 32][c0] = kv1;
    *(uint4*)&sV[r0][c0] = vv0;
    *(uint4*)&sV[r0 + 32][c0] = vv1;
    *(float4*)&sBi[rb][cb] = bv0;
    *(float4*)&sBi[rb + 16][cb] = bv1;
    *(float4*)&sBi[rb + 32][cb] = bv2;
    *(float4*)&sBi[rb + 48][cb] = bv3;
    __syncthreads();

    // S = Q K^T  (Q pre-scaled)
    f32x4 s[4];
#pragma unroll
    for (int fc = 0; fc < 4; ++fc) {
      bf16x8 kb0 = *(const bf16x8*)&sK[fc * 16 + t16][quad * 8];
      bf16x8 kb1 = *(const bf16x8*)&sK[fc * 16 + t16][32 + quad * 8];
      f32x4 z = (f32x4){0.f, 0.f, 0.f, 0.f};
      z = MFMA16(qa0, kb0, z);
      z = MFMA16(qa1, kb1, z);
      s[fc] = z;
    }
    // + pos_bias (fp32), causal mask
#pragma unroll
    for (int fc = 0; fc < 4; ++fc)
#pragma unroll
      for (int r = 0; r < 4; ++r) {
        float sv = s[fc][r] + sBi[wave * 16 + quad * 4 + r][fc * 16 + t16];
        if (k0 + fc * 16 + t16 > qrow + r) sv = -1e30f;
        s[fc][r] = sv;
      }
    // online softmax (row stats live in the 16 lanes of each quad)
    float mx[4];
#pragma unroll
    for (int r = 0; r < 4; ++r)
      mx[r] = fmaxf(fmaxf(s[0][r], s[1][r]), fmaxf(s[2][r], s[3][r]));
#pragma unroll
    for (int off = 1; off < 16; off <<= 1)
#pragma unroll
      for (int r = 0; r < 4; ++r) mx[r] = fmaxf(mx[r], __shfl_xor(mx[r], off));
    float al[4];
#pragma unroll
    for (int r = 0; r < 4; ++r) {
      float mn = fmaxf(m_r[r], mx[r]);
      al[r] = __expf(m_r[r] - mn);
      m_r[r] = mn;
    }
    float rs[4] = {0.f, 0.f, 0.f, 0.f};
#pragma unroll
    for (int fc = 0; fc < 4; ++fc)
#pragma unroll
      for (int r = 0; r < 4; ++r) {
        float p = __expf(s[fc][r] - m_r[r]);
        s[fc][r] = p;
        rs[r] += p;
      }
#pragma unroll
    for (int off = 1; off < 16; off <<= 1)
#pragma unroll
      for (int r = 0; r < 4; ++r) rs[r] += __shfl_xor(rs[r], off);
#pragma unroll
    for (int r = 0; r < 4; ++r) l_r[r] = l_r[r] * al[r] + rs[r];
#pragma unroll
    for (int fc = 0; fc < 4; ++fc)
#pragma unroll
      for (int r = 0; r < 4; ++r) accO[fc][r] *= al[r];
    // P: C-layout -> A-layout via LDS (bf16)
#pragma unroll
    for (int fc = 0; fc < 4; ++fc)
#pragma unroll
      for (int r = 0; r < 4; ++r)
        sP[wave][quad * 4 + r][fc * 16 + t16] = f2b(s[fc][r]);
    __syncthreads();
    const bf16x8 pa0 = *(const bf16x8*)&sP[wave][t16][quad * 8];
    const bf16x8 pa1 = *(const bf16x8*)&sP[wave][t16][32 + quad * 8];
#pragma unroll
    for (int fc = 0; fc < 4; ++fc) {
      bf16x8 vb0 = *(const bf16x8*)&sV[fc * 16 + t16][quad * 8];
      bf16x8 vb1 = *(const bf16x8*)&sV[fc * 16 + t16][32 + quad * 8];
      accO[fc] = MFMA16(pa0, vb0, accO[fc]);
      accO[fc] = MFMA16(pa1, vb1, accO[fc]);
    }
  }

  float inv[4];
#pragma unroll
  for (int r = 0; r < 4; ++r) inv[r] = 1.f / l_r[r];
  const size_t obase = (size_t)b * 2048 * 1024 + (size_t)h * 64;
#pragma unroll
  for (int fc = 0; fc < 4; ++fc)
#pragma unroll
    for (int r = 0; r < 4; ++r)
      Ao[obase + (size_t)(q0 + wave * 16 + quad * 4 + r) * 1024 + fc * 16 +
         t16] = f2b(accO[fc][r] * inv[r]);
}

extern "C" void kernel_launch(void* const* d_in, const int* in_sizes, int n_in,
                              void* d_out, int out_size, void* d_ws,
                              size_t ws_size, hipStream_t stream) {
  (void)in_sizes;
  (void)n_in;
  (void)out_size;
  (void)ws_size;
  const float* x = (const float*)d_in[0];
  const float* pb = (const float*)d_in[1];
  const float* wqkv = (const float*)d_in[2];
  const float* wpro = (const float*)d_in[3];
  const float* bpro = (const float*)d_in[4];

  unsigned short* ws = (unsigned short*)d_ws;
  unsigned short* wqkvT = ws;                   // 3072*1024 bf16
  unsigned short* wproT = wqkvT + 3072 * 1024;  // 1024*1024 bf16
  unsigned short* Qb = wproT + 1024 * 1024;     // [4,16,2048,64] bf16
  unsigned short* Kb = Qb + 8388608;            // [4,16,2048,64] bf16
  unsigned short* Vtb = Kb + 8388608;           // [4,16,64,2048] bf16
  unsigned short* Ao = Vtb + 8388608;           // [8192,1024] bf16

  transpose_f32_bf16<<<dim3(48, 16), 256, 0, stream>>>(wqkv, wqkvT, 1024, 3072);
  transpose_f32_bf16<<<dim3(16, 16), 256, 0, stream>>>(wpro, wproT, 1024, 1024);
  gemm_bt<0><<<dim3(24, 64), 256, 0, stream>>>(x, wqkvT, Qb, Kb, Vtb, nullptr,
                                               nullptr, 1024, 3072);
  attn_kernel<<<2048, 256, 0, stream>>>(Qb, Kb, Vtb, pb, Ao);
  gemm_bt<1><<<dim3(8, 64), 256, 0, stream>>>(Ao, wproT, nullptr, nullptr,
                                              nullptr, (float*)d_out, bpro,
                                              1024, 1024);
}

// Round 4
// 579.370 us; speedup vs baseline: 1.3574x; 1.3574x over previous
//
#include <hip/hip_runtime.h>
#include <hip/hip_bf16.h>
#include <math.h>

typedef __attribute__((ext_vector_type(8))) short bf16x8;
typedef __attribute__((ext_vector_type(4))) float f32x4;
typedef __attribute__((ext_vector_type(8))) unsigned short u16x8;

#define MFMA16(a, b, c) __builtin_amdgcn_mfma_f32_16x16x32_bf16(a, b, c, 0, 0, 0)
#define LOG2E 1.4426950408889634f

__device__ __forceinline__ unsigned short f2b(float f) {
  __hip_bfloat16 h = __float2bfloat16(f);
  return *reinterpret_cast<unsigned short*>(&h);
}

// load 8 fp32, return 8 bf16 packed in a uint4
__device__ __forceinline__ uint4 cvt8(const float* __restrict__ p) {
  float4 a = *(const float4*)p;
  float4 b = *(const float4*)(p + 4);
  union {
    unsigned short us[8];
    uint4 u;
  } r;
  r.us[0] = f2b(a.x); r.us[1] = f2b(a.y); r.us[2] = f2b(a.z); r.us[3] = f2b(a.w);
  r.us[4] = f2b(b.x); r.us[5] = f2b(b.y); r.us[6] = f2b(b.z); r.us[7] = f2b(b.w);
  return r.u;
}

// flat fp32 -> bf16 convert, 8 elems/thread
__global__ __launch_bounds__(256) void conv_f32_bf16(
    const float* __restrict__ in, unsigned short* __restrict__ out) {
  size_t i = ((size_t)blockIdx.x * 256 + threadIdx.x) * 8;
  *(uint4*)&out[i] = cvt8(in + i);
}

// out_bf16[c][r] = bf16(in_f32[r][c]); R, C multiples of 64
__global__ __launch_bounds__(256) void transpose_f32_bf16(
    const float* __restrict__ in, unsigned short* __restrict__ out, int R,
    int C) {
  __shared__ unsigned short tile[64][72];
  const int tR = blockIdx.y * 64, tC = blockIdx.x * 64;
  const int t = threadIdx.x;
#pragma unroll
  for (int p = 0; p < 4; ++p) {
    int u = t + p * 256, r = u >> 4, c = (u & 15) * 4;
    float4 v = *(const float4*)&in[(size_t)(tR + r) * C + tC + c];
    tile[r][c] = f2b(v.x);
    tile[r][c + 1] = f2b(v.y);
    tile[r][c + 2] = f2b(v.z);
    tile[r][c + 3] = f2b(v.w);
  }
  __syncthreads();
#pragma unroll
  for (int p = 0; p < 2; ++p) {
    int u = t + p * 256, orow = u >> 3, oc = (u & 7) * 8;
    u16x8 v;
#pragma unroll
    for (int e = 0; e < 8; ++e) v[e] = tile[oc + e][orow];
    *(u16x8*)&out[(size_t)(tC + orow) * R + tR + oc] = v;
  }
}

// C[M][N] = A[M][K] * Bt[N][K]^T, 128x128 tile, 4 waves, 16x16x32 MFMA.
// A is bf16. MODE 0: epilogue splits into Q*scale / K / V^T head layouts.
// MODE 1: epilogue adds fp32 bias, stores fp32 row-major.
template <int MODE>
__global__ __launch_bounds__(256, 2) void gemm_bt(
    const unsigned short* __restrict__ A, const unsigned short* __restrict__ Bt,
    unsigned short* __restrict__ O0, unsigned short* __restrict__ O1,
    unsigned short* __restrict__ O2, float* __restrict__ OF,
    const float* __restrict__ bias, int K, int N) {
  __shared__ unsigned short sA[128][40];
  __shared__ unsigned short sB[128][40];
  const int m0 = blockIdx.y * 128, n0 = blockIdx.x * 128;
  const int t = threadIdx.x;
  const int wave = t >> 6, lane = t & 63, quad = lane >> 4, t16 = lane & 15;
  const int wr = (wave >> 1) * 64, wc = (wave & 1) * 64;
  const int sr = t >> 2, sc = (t & 3) * 8;

  f32x4 acc[4][4];
#pragma unroll
  for (int i = 0; i < 4; ++i)
#pragma unroll
    for (int j = 0; j < 4; ++j) acc[i][j] = (f32x4){0.f, 0.f, 0.f, 0.f};

  const unsigned short* Ap = A + (size_t)(m0 + sr) * K + sc;
  const unsigned short* Bp = Bt + (size_t)(n0 + sr) * K + sc;
  const size_t rowK64 = (size_t)64 * K;

  for (int k0 = 0; k0 < K; k0 += 32) {
    uint4 a0 = *(const uint4*)(Ap + k0);
    uint4 a1 = *(const uint4*)(Ap + rowK64 + k0);
    uint4 b0 = *(const uint4*)(Bp + k0);
    uint4 b1 = *(const uint4*)(Bp + rowK64 + k0);
    __syncthreads();
    *(uint4*)&sA[sr][sc] = a0;
    *(uint4*)&sA[sr + 64][sc] = a1;
    *(uint4*)&sB[sr][sc] = b0;
    *(uint4*)&sB[sr + 64][sc] = b1;
    __syncthreads();
    bf16x8 af[4], bf[4];
#pragma unroll
    for (int i = 0; i < 4; ++i)
      af[i] = *(const bf16x8*)&sA[wr + i * 16 + t16][quad * 8];
#pragma unroll
    for (int j = 0; j < 4; ++j)
      bf[j] = *(const bf16x8*)&sB[wc + j * 16 + t16][quad * 8];
#pragma unroll
    for (int i = 0; i < 4; ++i)
#pragma unroll
      for (int j = 0; j < 4; ++j) acc[i][j] = MFMA16(af[i], bf[j], acc[i][j]);
  }

#pragma unroll
  for (int i = 0; i < 4; ++i) {
    const int mrow = m0 + wr + i * 16 + quad * 4;  // + r
#pragma unroll
    for (int j = 0; j < 4; ++j) {
      const int ncol = n0 + wc + j * 16 + t16;
#pragma unroll
      for (int r = 0; r < 4; ++r) {
        const float v = acc[i][j][r];
        const int mr = mrow + r;
        if (MODE == 0) {
          const int bb = mr >> 11, nn = mr & 2047;
          const int sec = ncol >> 10, rem = ncol & 1023;
          const int hh = rem >> 6, dd = rem & 63;
          const size_t bhh = (size_t)bb * 16 + hh;
          if (sec == 0)  // Q * (scale*log2e): softmax runs in log2 domain
            O0[(bhh * 2048 + nn) * 64 + dd] = f2b(v * (0.125f * LOG2E));
          else if (sec == 1)
            O1[(bhh * 2048 + nn) * 64 + dd] = f2b(v);  // K
          else
            O2[(bhh * 64 + dd) * 2048 + nn] = f2b(v);  // V^T
        } else {
          OF[(size_t)mr * N + ncol] = v + bias[ncol];
        }
      }
    }
  }
}

// Flash attention: block = (b,h, 64-row q tile), 4 waves of 16 q rows each.
// qt-major-descending dispatch order; K/V reg-prefetch pipeline; pos_bias
// loaded straight into C-layout registers; softmax in log2 domain.
__global__ __launch_bounds__(256, 4) void attn_kernel(
    const unsigned short* __restrict__ Q, const unsigned short* __restrict__ Kb,
    const unsigned short* __restrict__ Vt, const float* __restrict__ PB,
    unsigned short* __restrict__ Ao) {
  __shared__ unsigned short sK[64][72];
  __shared__ unsigned short sV[64][72];   // sV[d][key]
  __shared__ unsigned short sQP[64][72];  // Q staging, then per-wave P buffer

  const int bh = blockIdx.x & 63;
  const int qt = 31 - (blockIdx.x >> 6);  // heavy q-tiles dispatch first
  const int h = bh & 15;
  const int b = bh >> 4;
  const int q0 = qt * 64;
  const int t = threadIdx.x;
  const int wave = t >> 6, lane = t & 63, quad = lane >> 4, t16 = lane & 15;

  const size_t qbase = ((size_t)bh * 2048 + q0) * 64;
#pragma unroll
  for (int p = 0; p < 2; ++p) {
    int u = t + p * 256, r = u >> 3, c = (u & 7) * 8;
    *(uint4*)&sQP[r][c] = *(const uint4*)&Q[qbase + r * 64 + c];
  }
  __syncthreads();
  const bf16x8 qa0 = *(const bf16x8*)&sQP[wave * 16 + t16][quad * 8];
  const bf16x8 qa1 = *(const bf16x8*)&sQP[wave * 16 + t16][32 + quad * 8];
  // sQP is reused as P buffer inside the loop; iteration-0's two barriers
  // order every wave's Q-frag reads before the first P write.

  f32x4 accO[4];
  float m_r[4], l_r[4];
#pragma unroll
  for (int i = 0; i < 4; ++i) {
    accO[i] = (f32x4){0.f, 0.f, 0.f, 0.f};
    m_r[i] = -INFINITY;
    l_r[i] = 0.f;
  }

  const int qrow = q0 + wave * 16 + quad * 4;  // + r
  const int r0 = t >> 3, c0 = (t & 7) * 8;
  const size_t kvrow = (size_t)bh * 2048 * 64;
  const size_t bbase =
      (size_t)h * 4194304 + (size_t)q0 * 2048 + (wave * 16 + quad * 4) * 2048;

  // ---- prefetch tile 0 (K/V into regs, bias into C-layout regs) ----
  uint4 kv0 = *(const uint4*)&Kb[kvrow + (size_t)r0 * 64 + c0];
  uint4 kv1 = *(const uint4*)&Kb[kvrow + (size_t)(r0 + 32) * 64 + c0];
  uint4 vv0 = *(const uint4*)&Vt[kvrow + (size_t)r0 * 2048 + c0];
  uint4 vv1 = *(const uint4*)&Vt[kvrow + (size_t)(r0 + 32) * 2048 + c0];
  float biasr[4][4];
#pragma unroll
  for (int fc = 0; fc < 4; ++fc)
#pragma unroll
    for (int r = 0; r < 4; ++r)
      biasr[fc][r] = PB[bbase + (size_t)r * 2048 + fc * 16 + t16];

  for (int kt = 0; kt <= qt; ++kt) {
    const int k0 = kt * 64;
    __syncthreads();  // previous tile's LDS reads complete
    *(uint4*)&sK[r0][c0] = kv0;
    *(uint4*)&sK[r0 + 32][c0] = kv1;
    *(uint4*)&sV[r0][c0] = vv0;
    *(uint4*)&sV[r0 + 32][c0] = vv1;
    __syncthreads();
    // prefetch next tile's K/V (after the barrier so its vmcnt(0) drain
    // doesn't serialize them; they overlap the whole compute phase below)
    if (kt < qt) {
      const size_t nk = (size_t)(k0 + 64);
      kv0 = *(const uint4*)&Kb[kvrow + nk * 64 + (size_t)r0 * 64 + c0];
      kv1 = *(const uint4*)&Kb[kvrow + nk * 64 + (size_t)(r0 + 32) * 64 + c0];
      vv0 = *(const uint4*)&Vt[kvrow + nk + (size_t)r0 * 2048 + c0];
      vv1 = *(const uint4*)&Vt[kvrow + nk + (size_t)(r0 + 32) * 2048 + c0];
    }

    // S = Q K^T  (Q pre-scaled by scale*log2e)
    f32x4 s[4];
#pragma unroll
    for (int fc = 0; fc < 4; ++fc) {
      bf16x8 kb0 = *(const bf16x8*)&sK[fc * 16 + t16][quad * 8];
      bf16x8 kb1 = *(const bf16x8*)&sK[fc * 16 + t16][32 + quad * 8];
      f32x4 z = (f32x4){0.f, 0.f, 0.f, 0.f};
      z = MFMA16(qa0, kb0, z);
      z = MFMA16(qa1, kb1, z);
      s[fc] = z;
    }
    // + pos_bias*log2e (fma), causal mask
#pragma unroll
    for (int fc = 0; fc < 4; ++fc)
#pragma unroll
      for (int r = 0; r < 4; ++r) {
        float sv = fmaf(biasr[fc][r], LOG2E, s[fc][r]);
        if (k0 + fc * 16 + t16 > qrow + r) sv = -1e30f;
        s[fc][r] = sv;
      }
    // prefetch next tile's bias into regs
    if (kt < qt) {
#pragma unroll
      for (int fc = 0; fc < 4; ++fc)
#pragma unroll
        for (int r = 0; r < 4; ++r)
          biasr[fc][r] =
              PB[bbase + (size_t)r * 2048 + (k0 + 64) + fc * 16 + t16];
    }
    // online softmax in log2 domain (row stats in the 16 lanes of each quad)
    float mx[4];
#pragma unroll
    for (int r = 0; r < 4; ++r)
      mx[r] = fmaxf(fmaxf(s[0][r], s[1][r]), fmaxf(s[2][r], s[3][r]));
#pragma unroll
    for (int off = 1; off < 16; off <<= 1)
#pragma unroll
      for (int r = 0; r < 4; ++r) mx[r] = fmaxf(mx[r], __shfl_xor(mx[r], off));
    float al[4];
#pragma unroll
    for (int r = 0; r < 4; ++r) {
      float mn = fmaxf(m_r[r], mx[r]);
      al[r] = exp2f(m_r[r] - mn);
      m_r[r] = mn;
    }
    float rs[4] = {0.f, 0.f, 0.f, 0.f};
#pragma unroll
    for (int fc = 0; fc < 4; ++fc)
#pragma unroll
      for (int r = 0; r < 4; ++r) {
        float p = exp2f(s[fc][r] - m_r[r]);
        s[fc][r] = p;
        rs[r] += p;
      }
#pragma unroll
    for (int off = 1; off < 16; off <<= 1)
#pragma unroll
      for (int r = 0; r < 4; ++r) rs[r] += __shfl_xor(rs[r], off);
#pragma unroll
    for (int r = 0; r < 4; ++r) l_r[r] = l_r[r] * al[r] + rs[r];
#pragma unroll
    for (int fc = 0; fc < 4; ++fc)
#pragma unroll
      for (int r = 0; r < 4; ++r) accO[fc][r] *= al[r];
    // P: C-layout -> A-layout via per-wave LDS slice (no barrier needed:
    // same-wave DS ops are in-order; compiler inserts the lgkmcnt wait)
#pragma unroll
    for (int fc = 0; fc < 4; ++fc)
#pragma unroll
      for (int r = 0; r < 4; ++r)
        sQP[wave * 16 + quad * 4 + r][fc * 16 + t16] = f2b(s[fc][r]);
    const bf16x8 pa0 = *(const bf16x8*)&sQP[wave * 16 + t16][quad * 8];
    const bf16x8 pa1 = *(const bf16x8*)&sQP[wave * 16 + t16][32 + quad * 8];
#pragma unroll
    for (int fc = 0; fc < 4; ++fc) {
      bf16x8 vb0 = *(const bf16x8*)&sV[fc * 16 + t16][quad * 8];
      bf16x8 vb1 = *(const bf16x8*)&sV[fc * 16 + t16][32 + quad * 8];
      accO[fc] = MFMA16(pa0, vb0, accO[fc]);
      accO[fc] = MFMA16(pa1, vb1, accO[fc]);
    }
  }

  float inv[4];
#pragma unroll
  for (int r = 0; r < 4; ++r) inv[r] = 1.f / l_r[r];
  const size_t obase = (size_t)b * 2048 * 1024 + (size_t)h * 64;
#pragma unroll
  for (int fc = 0; fc < 4; ++fc)
#pragma unroll
    for (int r = 0; r < 4; ++r)
      Ao[obase + (size_t)(q0 + wave * 16 + quad * 4 + r) * 1024 + fc * 16 +
         t16] = f2b(accO[fc][r] * inv[r]);
}

extern "C" void kernel_launch(void* const* d_in, const int* in_sizes, int n_in,
                              void* d_out, int out_size, void* d_ws,
                              size_t ws_size, hipStream_t stream) {
  (void)in_sizes;
  (void)n_in;
  (void)out_size;
  (void)ws_size;
  const float* x = (const float*)d_in[0];
  const float* pb = (const float*)d_in[1];
  const float* wqkv = (const float*)d_in[2];
  const float* wpro = (const float*)d_in[3];
  const float* bpro = (const float*)d_in[4];

  unsigned short* ws = (unsigned short*)d_ws;
  unsigned short* wqkvT = ws;                   // 3072*1024 bf16
  unsigned short* wproT = wqkvT + 3072 * 1024;  // 1024*1024 bf16
  unsigned short* Qb = wproT + 1024 * 1024;     // [4,16,2048,64] bf16
  unsigned short* Kb = Qb + 8388608;            // [4,16,2048,64] bf16
  unsigned short* Vtb = Kb + 8388608;           // [4,16,64,2048] bf16
  unsigned short* Ao = Vtb + 8388608;           // [8192,1024] bf16
  unsigned short* xb = Ao;  // x-bf16 alias: dead before attn writes Ao

  conv_f32_bf16<<<4096, 256, 0, stream>>>(x, xb);
  transpose_f32_bf16<<<dim3(48, 16), 256, 0, stream>>>(wqkv, wqkvT, 1024, 3072);
  transpose_f32_bf16<<<dim3(16, 16), 256, 0, stream>>>(wpro, wproT, 1024, 1024);
  gemm_bt<0><<<dim3(24, 64), 256, 0, stream>>>(xb, wqkvT, Qb, Kb, Vtb, nullptr,
                                               nullptr, 1024, 3072);
  attn_kernel<<<2048, 256, 0, stream>>>(Qb, Kb, Vtb, pb, Ao);
  gemm_bt<1><<<dim3(8, 64), 256, 0, stream>>>(Ao, wproT, nullptr, nullptr,
                                              nullptr, (float*)d_out, bpro,
                                              1024, 1024);
}